// Round 11
// baseline (339.673 us; speedup 1.0000x reference)
//
#include <hip/hip_runtime.h>
#include <float.h>

#define NP 8192
#define CAP 64           // survivor slots per query (expected ~11-30)
#define NW 4             // waves per block
#define TB 256           // threads per block
#define CHUNK4 1024      // float4 candidates per chunk (16 KB)
#define NC (NP / CHUNK4) // 8 chunks
#define FQ 8             // fused kernel: queries/wave -> 256 blocks/pass
#define CQ 4             // cross kernel: queries/wave -> 512 blocks
typedef unsigned long long u64;

// ws float offsets
#define O_PC1  0          // float4[NP]: pc1  (x,y,z,|p|^2)
#define O_PC2  (4 * NP)   // float4[NP]: pc2
#define O_WARP (8 * NP)   // float4[NP]: warp
#define O_FLOW (12 * NP)  // float4[NP]: flow (w unused)
#define O_C2C  (16 * NP)  // SoA x,y,z: c2curv
#define O_MC   (19 * NP)  // SoA x,y,z: mcurv
#define O_ACC  (22 * NP)  // acc[0]=chamfer acc[1]=smooth acc[2]=curv

__device__ __forceinline__ float wavemin_f(float v) {
#pragma unroll
  for (int s = 1; s < 64; s <<= 1) v = fminf(v, __shfl_xor(v, s, 64));
  return v;
}

// score = |p|^2 - 2 p.q (nq = -2q); true sqdist = score + |q|^2.
__device__ __forceinline__ float score1(float4 c, float nx, float ny, float nz) {
  return fmaf(c.x, nx, fmaf(c.y, ny, fmaf(c.z, nz, c.w)));
}

// smallest remaining (s,j) across the wave; first-lane pick on exact ties.
__device__ __forceinline__ void extract1f(float& s, int& j, int lane,
                                          float& od, int& oj) {
  float w = wavemin_f(s);
  u64 msk = __ballot(s == w);
  int src = (int)__ffsll(msk) - 1;
  oj = __shfl(j, src, 64);
  if (lane == src) s = FLT_MAX;
  od = w;
}

// Async DMA stage: wave stages its 256-float4 quarter of a chunk as 4
// global_load_lds issues (wave-uniform LDS base + lane*16 linear dest,
// per-lane global src — m104 layout). No VGPR round-trip, counted by vmcnt.
__device__ __forceinline__ void stage_async(const float4* __restrict__ g,
                                            float4* s, int wave, int lane) {
#pragma unroll
  for (int k = 0; k < 4; ++k) {
    const float4* gp = g + (wave << 8) + (k << 6) + lane;
    float4* sp = s + (wave << 8) + (k << 6);
    __builtin_amdgcn_global_load_lds(
        (const __attribute__((address_space(1))) float*)gp,
        (__attribute__((address_space(3))) float*)sp, 16, 0, 0);
  }
}

// 2-phase pipeline step (T3/T4 minimal template): B1 = all waves done
// reading buf[cur^1]; issue next chunk's DMA into it; vmcnt(4) waits only
// the CURRENT chunk's 4 oldest loads (next 4 stay in flight across B2);
// raw s_barrier avoids __syncthreads' implicit vmcnt(0) drain; sched_barrier
// pins LDS reads below B2 (rule #18).
#define PIPE_STEP(c, candp)                                                  \
  __builtin_amdgcn_s_barrier();                                              \
  __builtin_amdgcn_sched_barrier(0);                                         \
  if ((c) + 1 < NC) {                                                        \
    stage_async((candp) + ((c) + 1) * CHUNK4, sbuf[((c) + 1) & 1], wave, lane); \
    asm volatile("s_waitcnt vmcnt(4)" ::: "memory");                         \
  } else {                                                                   \
    asm volatile("s_waitcnt vmcnt(0)" ::: "memory");                         \
  }                                                                          \
  __builtin_amdgcn_s_barrier();                                              \
  __builtin_amdgcn_sched_barrier(0);

// K-th smallest of the 64 lane-minima via value knockout. The K knocked-out
// lanes own K distinct candidates <= T, so the global K-th smallest <= T.
template<int K, int Q>
__device__ __forceinline__ void knockout(const float (&m)[Q], float (&T)[Q], int lane) {
#pragma unroll
  for (int q = 0; q < Q; ++q) {
    float mm = m[q], tv = 0.f;
#pragma unroll
    for (int r = 0; r < K; ++r) {
      float w = wavemin_f(mm);
      u64 msk = __ballot(mm == w);
      if (lane == (int)__ffsll(msk) - 1) mm = FLT_MAX;
      tv = w;
    }
    T[q] = tv;
  }
}

// Pipelined single scan: branchless per-lane minima.
template<int Q>
__device__ __forceinline__ void scan_min_pipe(const float4* __restrict__ cand,
                                              float4 (*sbuf)[CHUNK4],
                                              const float (&nqx)[Q],
                                              const float (&nqy)[Q],
                                              const float (&nqz)[Q],
                                              float (&m)[Q], int wave, int lane) {
#pragma unroll
  for (int q = 0; q < Q; ++q) m[q] = FLT_MAX;
  stage_async(cand, sbuf[0], wave, lane);
  for (int c = 0; c < NC; ++c) {
    PIPE_STEP(c, cand)
    const float4* sb = sbuf[c & 1];
#pragma unroll 4
    for (int g = 0; g < CHUNK4; g += 64) {
      float4 cc = sb[g + lane];
#pragma unroll
      for (int q = 0; q < Q; ++q)
        m[q] = fminf(m[q], score1(cc, nqx[q], nqy[q], nqz[q]));
    }
  }
}

// Pipelined collect scan: append every score <= T[q] to the wave's survivor
// list (slots pre-initialized to FLT_MAX; validity is data-derived).
template<int Q>
__device__ __forceinline__ void scan_collect_pipe(const float4* __restrict__ cand,
                                                  float4 (*sbuf)[CHUNK4],
                                                  const float (&nqx)[Q],
                                                  const float (&nqy)[Q],
                                                  const float (&nqz)[Q],
                                                  const float (&T)[Q],
                                                  float (*hs)[CAP], int (*hj)[CAP],
                                                  int* scnt, int wave, int lane) {
#pragma unroll
  for (int q = 0; q < Q; ++q) {
    hs[q][lane] = FLT_MAX;
    hj[q][lane] = 0;
    if (lane == 0) scnt[q] = 0;
  }
  stage_async(cand, sbuf[0], wave, lane);
  for (int c = 0; c < NC; ++c) {
    PIPE_STEP(c, cand)
    const float4* sb = sbuf[c & 1];
#pragma unroll 2
    for (int g = 0; g < CHUNK4; g += 64) {
      const int j = c * CHUNK4 + g + lane;
      float4 cc = sb[g + lane];
      float s[Q]; bool any = false;
#pragma unroll
      for (int q = 0; q < Q; ++q) {
        s[q] = score1(cc, nqx[q], nqy[q], nqz[q]);
        any |= (s[q] <= T[q]);
      }
      if (any) {
#pragma unroll
        for (int q = 0; q < Q; ++q) {
          if (s[q] <= T[q]) {
            int p = atomicAdd(scnt + q, 1);
            if (p < CAP) { hs[q][p] = s[q]; hj[q][p] = j; }
          }
        }
      }
    }
  }
  __syncthreads();  // drain survivor LDS writes before extraction reads
}

__global__ void k_prep(const float* __restrict__ pred, const float* __restrict__ gt,
                       const float* __restrict__ coords, float* __restrict__ ws) {
  int i = blockIdx.x * blockDim.x + threadIdx.x;
  if (i < NP) {
    float cx = coords[3 * i], cy = coords[3 * i + 1], cz = coords[3 * i + 2];
    float gx = gt[3 * i],     gy = gt[3 * i + 1],     gz = gt[3 * i + 2];
    float px = pred[3 * i],   py = pred[3 * i + 1],   pz = pred[3 * i + 2];
    float ax = cx + gx, ay = cy + gy, az = cz + gz;   // pc2
    float bx = cx + px, by = cy + py, bz = cz + pz;   // warp
    ((float4*)(ws + O_PC1))[i]  = make_float4(cx, cy, cz, cx * cx + cy * cy + cz * cz);
    ((float4*)(ws + O_PC2))[i]  = make_float4(ax, ay, az, ax * ax + ay * ay + az * az);
    ((float4*)(ws + O_WARP))[i] = make_float4(bx, by, bz, bx * bx + by * by + bz * bz);
    ((float4*)(ws + O_FLOW))[i] = make_float4(px, py, pz, 0.f);
  }
  if (i < 4) ws[O_ACC + i] = 0.f;
}

// fused: pass0 = pc2 x pc2 top-10 -> c2curv
//        pass1 = pc1 x pc1 top-10 -> mcurv (warp gather) + smooth (flow)
//        pass2 = pc2 x warp  min  -> chamfer dist2
// NO min-waves in __launch_bounds__ (R7/R8/R9's spill trigger).
__global__ __launch_bounds__(TB) void k_fused(float* __restrict__ ws) {
  __shared__ __align__(16) float4 sbuf[2][CHUNK4];
  __shared__ float hs[NW][FQ][CAP];
  __shared__ int   hj[NW][FQ][CAP];
  __shared__ int   scnt[NW][FQ];
  __shared__ float red[NW];
  const int pass = blockIdx.x % 3;
  const int pb   = blockIdx.x / 3;
  const int t = threadIdx.x;
  const int wave = t >> 6, lane = t & 63;
  const int i0 = pb * (NW * FQ) + wave * FQ;
  const float4* pc1q  = (const float4*)(ws + O_PC1);
  const float4* pc2q  = (const float4*)(ws + O_PC2);
  const float4* warpq = (const float4*)(ws + O_WARP);
  const float4* flowq = (const float4*)(ws + O_FLOW);

  if (pass == 2) {
    float nqx[FQ], nqy[FQ], nqz[FQ], qw[FQ], m[FQ];
#pragma unroll
    for (int q = 0; q < FQ; ++q) {
      float4 p = pc2q[i0 + q];
      nqx[q] = -2.f * p.x; nqy[q] = -2.f * p.y; nqz[q] = -2.f * p.z;
      qw[q] = p.w;
    }
    scan_min_pipe<FQ>(warpq, sbuf, nqx, nqy, nqz, m, wave, lane);
    float s = 0.f;
#pragma unroll
    for (int q = 0; q < FQ; ++q) s += wavemin_f(m[q]) + qw[q];
    if (lane == 0) red[wave] = s;
    __syncthreads();
    if (t == 0) {
      float t0 = 0.f;
#pragma unroll
      for (int w = 0; w < NW; ++w) t0 += red[w];
      atomicAdd(ws + O_ACC + 0, t0);
    }
    return;
  }

  const float4* cand = (pass == 0) ? pc2q : pc1q;
  float nqx[FQ], nqy[FQ], nqz[FQ], m[FQ], T[FQ];
#pragma unroll
  for (int q = 0; q < FQ; ++q) {
    float4 p = cand[i0 + q];
    nqx[q] = -2.f * p.x; nqy[q] = -2.f * p.y; nqz[q] = -2.f * p.z;
  }
  scan_min_pipe<FQ>(cand, sbuf, nqx, nqy, nqz, m, wave, lane);
  knockout<10, FQ>(m, T, lane);
  scan_collect_pipe<FQ>(cand, sbuf, nqx, nqy, nqz, T,
                        hs[wave], hj[wave], scnt[wave], wave, lane);

  if (pass == 0) {
#pragma unroll
    for (int q = 0; q < FQ; ++q) {
      float s = hs[wave][q][lane]; int j = hj[wave][q][lane];
      float ax = 0.f, ay = 0.f, az = 0.f;
#pragma unroll
      for (int r = 0; r < 10; ++r) {
        float od; int oj;
        extract1f(s, j, lane, od, oj);
        float4 g = pc2q[oj];
        ax += g.x; ay += g.y; az += g.z;
      }
      if (lane == 0) {
        const float inv9 = 1.f / 9.f;
        const int i = i0 + q;
        float qx = -0.5f * nqx[q], qy = -0.5f * nqy[q], qz = -0.5f * nqz[q];
        ws[O_C2C + 0 * NP + i] = (ax - 10.f * qx) * inv9;
        ws[O_C2C + 1 * NP + i] = (ay - 10.f * qy) * inv9;
        ws[O_C2C + 2 * NP + i] = (az - 10.f * qz) * inv9;
      }
    }
  } else {
    float smw = 0.f;
#pragma unroll
    for (int q = 0; q < FQ; ++q) {
      const int i = i0 + q;
      float4 wi = warpq[i];
      float4 fi = flowq[i];
      float s = hs[wave][q][lane]; int j = hj[wave][q][lane];
      float ax = 0.f, ay = 0.f, az = 0.f, sm = 0.f;
#pragma unroll
      for (int r = 0; r < 10; ++r) {
        float od; int oj;
        extract1f(s, j, lane, od, oj);
        float4 g = warpq[oj];
        ax += g.x; ay += g.y; az += g.z;
        if (r < 9) {
          float4 f = flowq[oj];
          float gx_ = f.x - fi.x, gy_ = f.y - fi.y, gz_ = f.z - fi.z;
          sm += sqrtf(gx_ * gx_ + gy_ * gy_ + gz_ * gz_);
        }
      }
      smw += sm * 0.125f;
      if (lane == 0) {
        const float inv9 = 1.f / 9.f;
        ws[O_MC + 0 * NP + i] = (ax - 10.f * wi.x) * inv9;
        ws[O_MC + 1 * NP + i] = (ay - 10.f * wi.y) * inv9;
        ws[O_MC + 2 * NP + i] = (az - 10.f * wi.z) * inv9;
      }
    }
    if (lane == 0) red[wave] = smw;
    __syncthreads();
    if (t == 0) {
      float s = 0.f;
#pragma unroll
      for (int w = 0; w < NW; ++w) s += red[w];
      atomicAdd(ws + O_ACC + 1, s);
    }
  }
}

// warp x pc2 top-5 -> chamfer dist1 + interpolated-curvature loss
__global__ __launch_bounds__(TB) void k_cross(float* __restrict__ ws) {
  __shared__ __align__(16) float4 sbuf[2][CHUNK4];
  __shared__ float hs[NW][CQ][CAP];
  __shared__ int   hj[NW][CQ][CAP];
  __shared__ int   scnt[NW][CQ];
  __shared__ float redc[NW], redv[NW];
  const float4* pc2q  = (const float4*)(ws + O_PC2);
  const float4* warpq = (const float4*)(ws + O_WARP);
  const int t = threadIdx.x;
  const int wave = t >> 6, lane = t & 63;
  const int i0 = blockIdx.x * (NW * CQ) + wave * CQ;
  float nqx[CQ], nqy[CQ], nqz[CQ], qw[CQ], m[CQ], T[CQ];
#pragma unroll
  for (int q = 0; q < CQ; ++q) {
    float4 p = warpq[i0 + q];
    nqx[q] = -2.f * p.x; nqy[q] = -2.f * p.y; nqz[q] = -2.f * p.z;
    qw[q] = p.w;
  }
  scan_min_pipe<CQ>(pc2q, sbuf, nqx, nqy, nqz, m, wave, lane);
  knockout<5, CQ>(m, T, lane);
  scan_collect_pipe<CQ>(pc2q, sbuf, nqx, nqy, nqz, T,
                        hs[wave], hj[wave], scnt[wave], wave, lane);
  float csum = 0.f, vsum = 0.f;
#pragma unroll
  for (int q = 0; q < CQ; ++q) {
    const int i = i0 + q;
    float s = hs[wave][q][lane]; int j = hj[wave][q][lane];
    float wsum = 0.f, ix = 0.f, iy = 0.f, iz = 0.f, d1 = 0.f;
#pragma unroll
    for (int r = 0; r < 5; ++r) {
      float od; int oj;
      extract1f(s, j, lane, od, oj);
      float d = od + qw[q];           // true squared distance
      if (r == 0) d1 = d;
      float wt = 1.f / (d + 1e-8f);
      wsum += wt;
      ix += wt * ws[O_C2C + 0 * NP + oj];
      iy += wt * ws[O_C2C + 1 * NP + oj];
      iz += wt * ws[O_C2C + 2 * NP + oj];
    }
    float inv = 1.f / wsum;
    float ex = ix * inv - ws[O_MC + 0 * NP + i];
    float ey = iy * inv - ws[O_MC + 1 * NP + i];
    float ez = iz * inv - ws[O_MC + 2 * NP + i];
    csum += d1;
    vsum += ex * ex + ey * ey + ez * ez;
  }
  if (lane == 0) { redc[wave] = csum; redv[wave] = vsum; }
  __syncthreads();
  if (t == 0) {
    float sc = 0.f, sv = 0.f;
#pragma unroll
    for (int w = 0; w < NW; ++w) { sc += redc[w]; sv += redv[w]; }
    atomicAdd(ws + O_ACC + 0, sc);
    atomicAdd(ws + O_ACC + 2, sv);
  }
}

__global__ void k_final(const float* __restrict__ ws, float* __restrict__ out) {
  float ch = ws[O_ACC + 0];
  float sm = ws[O_ACC + 1];
  float cv = ws[O_ACC + 2];
  out[0] = 0.02f * ch + 0.02f * 0.3f * cv + 0.02f * sm;
}

extern "C" void kernel_launch(void* const* d_in, const int* in_sizes, int n_in,
                              void* d_out, int out_size, void* d_ws, size_t ws_size,
                              hipStream_t stream) {
  (void)in_sizes; (void)n_in; (void)out_size; (void)ws_size;
  const float* pred   = (const float*)d_in[0];
  const float* gt     = (const float*)d_in[1];
  const float* coords = (const float*)d_in[2];
  float* ws  = (float*)d_ws;
  float* out = (float*)d_out;

  k_prep<<<dim3(NP / TB), dim3(TB), 0, stream>>>(pred, gt, coords, ws);
  k_fused<<<dim3(3 * (NP / (NW * FQ))), dim3(TB), 0, stream>>>(ws);
  k_cross<<<dim3(NP / (NW * CQ)), dim3(TB), 0, stream>>>(ws);
  k_final<<<1, 1, 0, stream>>>(ws, out);
}

// Round 12
// 172.049 us; speedup vs baseline: 1.9743x; 1.9743x over previous
//
#include <hip/hip_runtime.h>
#include <float.h>

#define NP 8192
#define WPB 4            // waves per block
#define BLK (WPB * 64)   // 256 threads
#define QPW 4            // queries per wave
#define QPB (WPB * QPW)  // 16 queries per block
#define NBLK (NP / QPB)  // 512 blocks -> 2 blocks/CU
#define CHUNK 2048       // candidates per LDS chunk (32 KB xyzw SoA)
#define CAP2 64          // survivor slots per query (expected ~29)

typedef unsigned long long u64;

// ws layout (floats):
//  0..3  *NP  pc1  x,y,z,w(|p|^2)
//  4..7  *NP  pc2  x,y,z,w
//  8..11 *NP  warp x,y,z,w
// 12..14 *NP  flow x,y,z
// 15..17 *NP  c2curv x,y,z
// 18..20 *NP  mcurv  x,y,z
// 21*NP      acc[0]=chamfer acc[1]=smooth acc[2]=curv

__device__ __forceinline__ float wavemin_f(float v) {
#pragma unroll
  for (int s = 1; s < 64; s <<= 1) v = fminf(v, __shfl_xor(v, s, 64));
  return v;
}

__device__ __forceinline__ float wavesum_f(float v) {
#pragma unroll
  for (int s = 1; s < 64; s <<= 1) v += __shfl_xor(v, s, 64);
  return v;
}

// monotone float->u32 map (handles negatives; no NaNs in this data)
__device__ __forceinline__ unsigned mono(float f) {
  unsigned u = __float_as_uint(f);
  return u ^ ((unsigned)((int)u >> 31) | 0x80000000u);
}
__device__ __forceinline__ float mono_inv(unsigned x) {
  unsigned u = x ^ ((unsigned)((int)(~x) >> 31) | 0x80000000u);
  return __uint_as_float(u);
}

// full-wave bitonic sort (ascending by lane) of u64 keys; 21 shfl stages.
__device__ __forceinline__ u64 sort64(u64 key, int lane) {
#pragma unroll
  for (int k = 2; k <= 64; k <<= 1) {
#pragma unroll
    for (int j = k >> 1; j > 0; j >>= 1) {
      u64 o = __shfl_xor(key, j, 64);
      bool up = ((lane & k) == 0);
      bool lower = ((lane & j) == 0);
      u64 mn = (o < key) ? o : key;
      u64 mx = (o < key) ? key : o;
      key = (lower == up) ? mn : mx;
    }
  }
  return key;
}

// Valid top-K threshold in ~9 shuffles: T = max of K group-minima.
// Each group-min IS a distinct candidate <= T, so the true K-th smallest <= T.
template<int K>
__device__ __forceinline__ float thresholdK(float m, int lane) {
  constexpr int GS = (K <= 8) ? 8 : 4;   // group size; need GS*K <= 64
  float gm = fminf(m, __shfl_xor(m, 1, 64));
  gm = fminf(gm, __shfl_xor(gm, 2, 64));
  if constexpr (GS == 8) gm = fminf(gm, __shfl_xor(gm, 4, 64));
  float v = (lane < GS * K) ? gm : -FLT_MAX;
#pragma unroll
  for (int s = 1; s < 64; s <<= 1) v = fmaxf(v, __shfl_xor(v, s, 64));
  return v;
}

// score = |p|^2 - 2 p.q  (nq* = -2*q*); true d = score + |q|^2. Identical FMA
// sequence in scan1/scan2 so threshold compares are bitwise-consistent.
__device__ __forceinline__ float score1(float x, float y, float z, float w,
                                        float nx, float ny, float nz) {
  return fmaf(x, nx, fmaf(y, ny, fmaf(z, nz, w)));
}

// 256 threads stage CHUNK=2048 floats per array
__device__ __forceinline__ void stage4(const float* __restrict__ gx,
                                       const float* __restrict__ gy,
                                       const float* __restrict__ gz,
                                       const float* __restrict__ gw,
                                       float* sx, float* sy, float* sz, float* sw) {
  const int t = threadIdx.x * 4;
#pragma unroll
  for (int h = 0; h < CHUNK; h += 1024) {
    *(float4*)(sx + t + h) = *(const float4*)(gx + t + h);
    *(float4*)(sy + t + h) = *(const float4*)(gy + t + h);
    *(float4*)(sz + t + h) = *(const float4*)(gz + t + h);
    *(float4*)(sw + t + h) = *(const float4*)(gw + t + h);
  }
}

// Two-scan filter for QPW queries per wave (R4-proven structure).
// scan1: branchless per-lane min score. T[q] = thresholdK (valid bound).
// scan2: every score <= T[q] appended via LDS atomic counter; slots
//   pre-initialized to FLT_MAX so validity is data-derived.
template<int K>
__device__ __forceinline__ void wave_filter(const float* __restrict__ px,
                                            const float* __restrict__ py,
                                            const float* __restrict__ pz,
                                            const float* __restrict__ pw,
                                            const float (&nqx)[QPW],
                                            const float (&nqy)[QPW],
                                            const float (&nqz)[QPW],
                                            float* sx, float* sy, float* sz, float* sw,
                                            float (*hs)[CAP2], int (*hj)[CAP2],
                                            int* scnt) {
  const int lane = threadIdx.x & 63;
  float m[QPW];
#pragma unroll
  for (int q = 0; q < QPW; ++q) m[q] = FLT_MAX;

  // ---- scan 1 ----
  for (int c = 0; c < NP; c += CHUNK) {
    __syncthreads();
    stage4(px + c, py + c, pz + c, pw + c, sx, sy, sz, sw);
    __syncthreads();
#pragma unroll 4
    for (int g = 0; g < CHUNK; g += 256) {
      const int o = g + 4 * lane;
      float4 X = *(const float4*)(sx + o);
      float4 Y = *(const float4*)(sy + o);
      float4 Z = *(const float4*)(sz + o);
      float4 W = *(const float4*)(sw + o);
#pragma unroll
      for (int q = 0; q < QPW; ++q) {
        float s0 = score1(X.x, Y.x, Z.x, W.x, nqx[q], nqy[q], nqz[q]);
        float s1 = score1(X.y, Y.y, Z.y, W.y, nqx[q], nqy[q], nqz[q]);
        float s2 = score1(X.z, Y.z, Z.z, W.z, nqx[q], nqy[q], nqz[q]);
        float s3 = score1(X.w, Y.w, Z.w, W.w, nqx[q], nqy[q], nqz[q]);
        m[q] = fminf(m[q], fminf(fminf(s0, s1), fminf(s2, s3)));
      }
    }
  }

  // ---- parallel threshold (replaces serial knockout) ----
  float T[QPW];
#pragma unroll
  for (int q = 0; q < QPW; ++q) T[q] = thresholdK<K>(m[q], lane);

  // ---- init survivor buffers ----
#pragma unroll
  for (int q = 0; q < QPW; ++q) {
    hs[q][lane] = FLT_MAX;
    hj[q][lane] = 0;
    if (lane == 0) scnt[q] = 0;
  }

  // ---- scan 2: collect all score <= T[q] ----
  for (int c = 0; c < NP; c += CHUNK) {
    __syncthreads();
    stage4(px + c, py + c, pz + c, pw + c, sx, sy, sz, sw);
    __syncthreads();
#pragma unroll 4
    for (int g = 0; g < CHUNK; g += 256) {
      const int o = g + 4 * lane;
      const int base = c + o;
      float4 X = *(const float4*)(sx + o);
      float4 Y = *(const float4*)(sy + o);
      float4 Z = *(const float4*)(sz + o);
      float4 W = *(const float4*)(sw + o);
#pragma unroll
      for (int q = 0; q < QPW; ++q) {
        float s0 = score1(X.x, Y.x, Z.x, W.x, nqx[q], nqy[q], nqz[q]);
        float s1 = score1(X.y, Y.y, Z.y, W.y, nqx[q], nqy[q], nqz[q]);
        float s2 = score1(X.z, Y.z, Z.z, W.z, nqx[q], nqy[q], nqz[q]);
        float s3 = score1(X.w, Y.w, Z.w, W.w, nqx[q], nqy[q], nqz[q]);
        float gm = fminf(fminf(s0, s1), fminf(s2, s3));
        if (__ballot(gm <= T[q]) != 0ULL) {
          if (s0 <= T[q]) { int p = atomicAdd(scnt + q, 1); if (p < CAP2) { hs[q][p] = s0; hj[q][p] = base + 0; } }
          if (s1 <= T[q]) { int p = atomicAdd(scnt + q, 1); if (p < CAP2) { hs[q][p] = s1; hj[q][p] = base + 1; } }
          if (s2 <= T[q]) { int p = atomicAdd(scnt + q, 1); if (p < CAP2) { hs[q][p] = s2; hj[q][p] = base + 2; } }
          if (s3 <= T[q]) { int p = atomicAdd(scnt + q, 1); if (p < CAP2) { hs[q][p] = s3; hj[q][p] = base + 3; } }
        }
      }
    }
  }
  __syncthreads();  // survivor writes visible before extraction
}

__global__ void k_prep(const float* __restrict__ pred, const float* __restrict__ gt,
                       const float* __restrict__ coords, float* __restrict__ ws) {
  int i = blockIdx.x * blockDim.x + threadIdx.x;
  if (i < NP) {
    float cx = coords[3 * i], cy = coords[3 * i + 1], cz = coords[3 * i + 2];
    float gx = gt[3 * i],     gy = gt[3 * i + 1],     gz = gt[3 * i + 2];
    float px = pred[3 * i],   py = pred[3 * i + 1],   pz = pred[3 * i + 2];
    float ax = cx + gx, ay = cy + gy, az = cz + gz;   // pc2
    float bx = cx + px, by = cy + py, bz = cz + pz;   // warp
    ws[0 * NP + i] = cx; ws[1 * NP + i] = cy; ws[2 * NP + i] = cz;
    ws[3 * NP + i] = cx * cx + cy * cy + cz * cz;
    ws[4 * NP + i] = ax; ws[5 * NP + i] = ay; ws[6 * NP + i] = az;
    ws[7 * NP + i] = ax * ax + ay * ay + az * az;
    ws[8 * NP + i] = bx; ws[9 * NP + i] = by; ws[10 * NP + i] = bz;
    ws[11 * NP + i] = bx * bx + by * by + bz * bz;
    ws[12 * NP + i] = px; ws[13 * NP + i] = py; ws[14 * NP + i] = pz;
  }
  if (i < 4) ws[21 * NP + i] = 0.f;
}

// pass 1: pc2 x pc2 top-10 -> c2curv
__global__ __launch_bounds__(BLK) void k_curv_pc2(float* __restrict__ ws) {
  __shared__ __align__(16) float sx[CHUNK], sy[CHUNK], sz[CHUNK], sw[CHUNK];
  __shared__ float hs[WPB][QPW][CAP2];
  __shared__ int hj[WPB][QPW][CAP2];
  __shared__ int scnt[WPB][QPW];
  const float* px = ws + 4 * NP; const float* py = ws + 5 * NP;
  const float* pz = ws + 6 * NP; const float* pw = ws + 7 * NP;
  const int wave = threadIdx.x >> 6, lane = threadIdx.x & 63;
  const int i0 = blockIdx.x * QPB + wave * QPW;
  float qx[QPW], qy[QPW], qz[QPW], nqx[QPW], nqy[QPW], nqz[QPW];
#pragma unroll
  for (int q = 0; q < QPW; ++q) {
    qx[q] = px[i0 + q]; qy[q] = py[i0 + q]; qz[q] = pz[i0 + q];
    nqx[q] = -2.f * qx[q]; nqy[q] = -2.f * qy[q]; nqz[q] = -2.f * qz[q];
  }
  wave_filter<10>(px, py, pz, pw, nqx, nqy, nqz, sx, sy, sz, sw,
                  hs[wave], hj[wave], scnt[wave]);
#pragma unroll
  for (int q = 0; q < QPW; ++q) {
    u64 key = ((u64)mono(hs[wave][q][lane]) << 32) | (unsigned)hj[wave][q][lane];
    key = sort64(key, lane);                 // lanes 0..9 = exact top-10 in order
    int oj = (int)(key & 0xffffffffu);
    float ax = 0.f, ay = 0.f, az = 0.f;
    if (lane < 10) { ax = px[oj]; ay = py[oj]; az = pz[oj]; }
    ax = wavesum_f(ax); ay = wavesum_f(ay); az = wavesum_f(az);
    if (lane == 0) {
      const float inv9 = 1.f / 9.f;
      const int i = i0 + q;
      ws[15 * NP + i] = (ax - 10.f * qx[q]) * inv9;
      ws[16 * NP + i] = (ay - 10.f * qy[q]) * inv9;
      ws[17 * NP + i] = (az - 10.f * qz[q]) * inv9;
    }
  }
}

// pass 2: pc1 x pc1 top-10 -> mcurv (gather warp) + smooth (top-9, flow norms)
__global__ __launch_bounds__(BLK) void k_pc1(float* __restrict__ ws) {
  __shared__ __align__(16) float sx[CHUNK], sy[CHUNK], sz[CHUNK], sw[CHUNK];
  __shared__ float hs[WPB][QPW][CAP2];
  __shared__ int hj[WPB][QPW][CAP2];
  __shared__ int scnt[WPB][QPW];
  __shared__ float red[WPB];
  const float* px = ws + 0 * NP; const float* py = ws + 1 * NP;
  const float* pz = ws + 2 * NP; const float* pw = ws + 3 * NP;
  const float* wx = ws + 8 * NP; const float* wy = ws + 9 * NP;
  const float* wz = ws + 10 * NP;
  const float* fx = ws + 12 * NP; const float* fy = ws + 13 * NP;
  const float* fz = ws + 14 * NP;
  const int wave = threadIdx.x >> 6, lane = threadIdx.x & 63;
  const int i0 = blockIdx.x * QPB + wave * QPW;
  float nqx[QPW], nqy[QPW], nqz[QPW];
#pragma unroll
  for (int q = 0; q < QPW; ++q) {
    nqx[q] = -2.f * px[i0 + q]; nqy[q] = -2.f * py[i0 + q]; nqz[q] = -2.f * pz[i0 + q];
  }
  wave_filter<10>(px, py, pz, pw, nqx, nqy, nqz, sx, sy, sz, sw,
                  hs[wave], hj[wave], scnt[wave]);
  float smw = 0.f;
#pragma unroll
  for (int q = 0; q < QPW; ++q) {
    const int i = i0 + q;
    const float fix = fx[i], fiy = fy[i], fiz = fz[i];
    const float wix = wx[i], wiy = wy[i], wiz = wz[i];
    u64 key = ((u64)mono(hs[wave][q][lane]) << 32) | (unsigned)hj[wave][q][lane];
    key = sort64(key, lane);
    int oj = (int)(key & 0xffffffffu);
    float ax = 0.f, ay = 0.f, az = 0.f, sm = 0.f;
    if (lane < 10) { ax = wx[oj]; ay = wy[oj]; az = wz[oj]; }
    if (lane < 9) {
      float gx_ = fx[oj] - fix, gy_ = fy[oj] - fiy, gz_ = fz[oj] - fiz;
      sm = sqrtf(gx_ * gx_ + gy_ * gy_ + gz_ * gz_);
    }
    ax = wavesum_f(ax); ay = wavesum_f(ay); az = wavesum_f(az);
    sm = wavesum_f(sm);
    smw += sm * 0.125f;
    if (lane == 0) {
      const float inv9 = 1.f / 9.f;
      ws[18 * NP + i] = (ax - 10.f * wix) * inv9;
      ws[19 * NP + i] = (ay - 10.f * wiy) * inv9;
      ws[20 * NP + i] = (az - 10.f * wiz) * inv9;
    }
  }
  if (lane == 0) red[wave] = smw;
  __syncthreads();
  if (threadIdx.x == 0) {
    float s = 0.f;
#pragma unroll
    for (int t = 0; t < WPB; ++t) s += red[t];
    atomicAdd(ws + 21 * NP + 1, s);
  }
}

// pass 3: warp x pc2 top-5 -> chamfer dist1 + interpolated-curvature loss
__global__ __launch_bounds__(BLK) void k_cross(float* __restrict__ ws) {
  __shared__ __align__(16) float sx[CHUNK], sy[CHUNK], sz[CHUNK], sw[CHUNK];
  __shared__ float hs[WPB][QPW][CAP2];
  __shared__ int hj[WPB][QPW][CAP2];
  __shared__ int scnt[WPB][QPW];
  __shared__ float redc[WPB], redv[WPB];
  const float* px = ws + 4 * NP; const float* py = ws + 5 * NP;
  const float* pz = ws + 6 * NP; const float* pw = ws + 7 * NP;   // pc2 cands
  const float* wx = ws + 8 * NP; const float* wy = ws + 9 * NP;
  const float* wz = ws + 10 * NP; const float* ww = ws + 11 * NP; // warp queries
  const float* cx = ws + 15 * NP; const float* cy = ws + 16 * NP;
  const float* cz = ws + 17 * NP;                                 // c2curv
  const float* mx = ws + 18 * NP; const float* my = ws + 19 * NP;
  const float* mz = ws + 20 * NP;                                 // mcurv
  const int wave = threadIdx.x >> 6, lane = threadIdx.x & 63;
  const int i0 = blockIdx.x * QPB + wave * QPW;
  float nqx[QPW], nqy[QPW], nqz[QPW], qw[QPW];
#pragma unroll
  for (int q = 0; q < QPW; ++q) {
    nqx[q] = -2.f * wx[i0 + q]; nqy[q] = -2.f * wy[i0 + q]; nqz[q] = -2.f * wz[i0 + q];
    qw[q] = ww[i0 + q];
  }
  wave_filter<5>(px, py, pz, pw, nqx, nqy, nqz, sx, sy, sz, sw,
                 hs[wave], hj[wave], scnt[wave]);
  float csum = 0.f, vsum = 0.f;
#pragma unroll
  for (int q = 0; q < QPW; ++q) {
    const int i = i0 + q;
    u64 key = ((u64)mono(hs[wave][q][lane]) << 32) | (unsigned)hj[wave][q][lane];
    key = sort64(key, lane);                 // lanes 0..4 = exact top-5 in order
    int oj = (int)(key & 0xffffffffu);
    float sc = mono_inv((unsigned)(key >> 32));
    float d = sc + qw[q];                    // true squared distance
    float wt = 0.f, ixx = 0.f, iyy = 0.f, izz = 0.f, d1 = 0.f;
    if (lane < 5) {
      wt = 1.f / (d + 1e-8f);
      ixx = wt * cx[oj]; iyy = wt * cy[oj]; izz = wt * cz[oj];
      if (lane == 0) d1 = d;
    }
    float wsum = wavesum_f(wt);
    ixx = wavesum_f(ixx); iyy = wavesum_f(iyy); izz = wavesum_f(izz);
    d1 = wavesum_f(d1);
    float inv = 1.f / wsum;
    float ex = ixx * inv - mx[i];
    float ey = iyy * inv - my[i];
    float ez = izz * inv - mz[i];
    csum += d1;
    vsum += ex * ex + ey * ey + ez * ez;
  }
  if (lane == 0) { redc[wave] = csum; redv[wave] = vsum; }
  __syncthreads();
  if (threadIdx.x == 0) {
    float sc = 0.f, sv = 0.f;
#pragma unroll
    for (int t = 0; t < WPB; ++t) { sc += redc[t]; sv += redv[t]; }
    atomicAdd(ws + 21 * NP + 0, sc);
    atomicAdd(ws + 21 * NP + 2, sv);
  }
}

// pass 4: pc2 x warp top-1 -> chamfer dist2 (branchless single scan)
__global__ __launch_bounds__(BLK) void k_rev(float* __restrict__ ws) {
  __shared__ __align__(16) float sx[CHUNK], sy[CHUNK], sz[CHUNK], sw[CHUNK];
  __shared__ float red[WPB];
  const float* px = ws + 8 * NP; const float* py = ws + 9 * NP;
  const float* pz = ws + 10 * NP; const float* pw = ws + 11 * NP; // warp cands
  const float* gx = ws + 4 * NP; const float* gy = ws + 5 * NP;
  const float* gz = ws + 6 * NP; const float* gw = ws + 7 * NP;   // pc2 queries
  const int wave = threadIdx.x >> 6, lane = threadIdx.x & 63;
  const int i0 = blockIdx.x * QPB + wave * QPW;
  float nqx[QPW], nqy[QPW], nqz[QPW], qw[QPW], m[QPW];
#pragma unroll
  for (int q = 0; q < QPW; ++q) {
    nqx[q] = -2.f * gx[i0 + q]; nqy[q] = -2.f * gy[i0 + q]; nqz[q] = -2.f * gz[i0 + q];
    qw[q] = gw[i0 + q];
    m[q] = FLT_MAX;
  }
  for (int c = 0; c < NP; c += CHUNK) {
    __syncthreads();
    stage4(px + c, py + c, pz + c, pw + c, sx, sy, sz, sw);
    __syncthreads();
#pragma unroll 4
    for (int g = 0; g < CHUNK; g += 256) {
      const int o = g + 4 * lane;
      float4 X = *(const float4*)(sx + o);
      float4 Y = *(const float4*)(sy + o);
      float4 Z = *(const float4*)(sz + o);
      float4 W = *(const float4*)(sw + o);
#pragma unroll
      for (int q = 0; q < QPW; ++q) {
        float s0 = score1(X.x, Y.x, Z.x, W.x, nqx[q], nqy[q], nqz[q]);
        float s1 = score1(X.y, Y.y, Z.y, W.y, nqx[q], nqy[q], nqz[q]);
        float s2 = score1(X.z, Y.z, Z.z, W.z, nqx[q], nqy[q], nqz[q]);
        float s3 = score1(X.w, Y.w, Z.w, W.w, nqx[q], nqy[q], nqz[q]);
        m[q] = fminf(m[q], fminf(fminf(s0, s1), fminf(s2, s3)));
      }
    }
  }
  float s = 0.f;
#pragma unroll
  for (int q = 0; q < QPW; ++q) s += wavemin_f(m[q]) + qw[q];
  if (lane == 0) red[wave] = s;
  __syncthreads();
  if (threadIdx.x == 0) {
    float t0 = 0.f;
#pragma unroll
    for (int t = 0; t < WPB; ++t) t0 += red[t];
    atomicAdd(ws + 21 * NP + 0, t0);
  }
}

__global__ void k_final(const float* __restrict__ ws, float* __restrict__ out) {
  float ch = ws[21 * NP + 0];
  float sm = ws[21 * NP + 1];
  float cv = ws[21 * NP + 2];
  out[0] = 0.02f * ch + 0.02f * 0.3f * cv + 0.02f * sm;
}

extern "C" void kernel_launch(void* const* d_in, const int* in_sizes, int n_in,
                              void* d_out, int out_size, void* d_ws, size_t ws_size,
                              hipStream_t stream) {
  (void)in_sizes; (void)n_in; (void)out_size; (void)ws_size;
  const float* pred   = (const float*)d_in[0];
  const float* gt     = (const float*)d_in[1];
  const float* coords = (const float*)d_in[2];
  float* ws  = (float*)d_ws;
  float* out = (float*)d_out;

  k_prep<<<dim3((NP + BLK - 1) / BLK), dim3(BLK), 0, stream>>>(pred, gt, coords, ws);
  dim3 g(NBLK), b(BLK);
  k_curv_pc2<<<g, b, 0, stream>>>(ws);
  k_pc1<<<g, b, 0, stream>>>(ws);
  k_rev<<<g, b, 0, stream>>>(ws);
  k_cross<<<g, b, 0, stream>>>(ws);
  k_final<<<1, 1, 0, stream>>>(ws, out);
}